// Round 9
// baseline (224.874 us; speedup 1.0000x reference)
//
#include <hip/hip_runtime.h>
#include <stdint.h>

typedef __attribute__((ext_vector_type(4))) int int4v;

// ---------- helpers ----------

__device__ __forceinline__ int pack4_rn(float4 v, float s) {
    int a = __float2int_rn(v.x * s) & 0xff;
    int b = __float2int_rn(v.y * s) & 0xff;
    int c = __float2int_rn(v.z * s) & 0xff;
    int d = __float2int_rn(v.w * s) & 0xff;
    return a | (b << 8) | (c << 16) | (d << 24);
}

__device__ __forceinline__ int bin4(float4 v) {
    int a = (v.x > 0.5f) ? 1 : 0;
    int b = (v.y > 0.5f) ? 1 : 0;
    int c = (v.z > 0.5f) ? 1 : 0;
    int d = (v.w > 0.5f) ? 1 : 0;
    return a | (b << 8) | (c << 16) | (d << 24);
}

// ---------- pre-pass: x (f32) -> per-row-quantized i8 + rscale ----------

__global__ __launch_bounds__(256) void lb_quant_x(const float* __restrict__ x,
        signed char* __restrict__ xq, float* __restrict__ rscale, int K)
{
    const int row = blockIdx.x;
    const int tid = threadIdx.x;
    const float* xr = x + (size_t)row * K;

    float mx = 0.f;
    for (int i = tid * 4; i < K; i += 256 * 4) {
        float4 v = *(const float4*)(xr + i);
        mx = fmaxf(mx, fmaxf(fmaxf(fabsf(v.x), fabsf(v.y)),
                             fmaxf(fabsf(v.z), fabsf(v.w))));
    }
#pragma unroll
    for (int s = 32; s; s >>= 1) mx = fmaxf(mx, __shfl_xor(mx, s));
    __shared__ float wmax[4];
    if ((tid & 63) == 0) wmax[tid >> 6] = mx;
    __syncthreads();
    mx = fmaxf(fmaxf(wmax[0], wmax[1]), fmaxf(wmax[2], wmax[3]));

    const float s = (mx > 0.f) ? 127.f / mx : 0.f;
    if (tid == 0) rscale[row] = (mx > 0.f) ? mx * (1.f / 127.f) : 0.f;

    for (int i = tid * 16; i < K; i += 256 * 16) {
        float4 a = *(const float4*)(xr + i);
        float4 b = *(const float4*)(xr + i + 4);
        float4 c = *(const float4*)(xr + i + 8);
        float4 d = *(const float4*)(xr + i + 12);
        int4 o;
        o.x = pack4_rn(a, s); o.y = pack4_rn(b, s);
        o.z = pack4_rn(c, s); o.w = pack4_rn(d, s);
        *(int4*)(xq + (size_t)row * K + i) = o;
    }
}

// ---------- pre-pass: w (f32) -> binarized i8 {0,1} ----------

__global__ void lb_bin_w8(const float* __restrict__ w, int4* __restrict__ wq, long n16) {
    long i = (long)blockIdx.x * blockDim.x + threadIdx.x;
    long stride = (long)gridDim.x * blockDim.x;
    for (; i < n16; i += stride) {
        const float4* p = (const float4*)w + i * 4;
        float4 v0 = p[0], v1 = p[1], v2 = p[2], v3 = p[3];
        int4 o;
        o.x = bin4(v0); o.y = bin4(v1); o.z = bin4(v2); o.w = bin4(v3);
        wq[i] = o;
    }
}

// ---------- main GEMM (i8): 128x128 tile, BK=64, 4 waves of 64x64 ----------
// KEY CHANGE vs R8: 256-thread blocks with 32 KiB LDS -> 4-5 blocks/CU
// co-resident. Each SIMD hosts waves from ~4 INDEPENDENT blocks, so when one
// block stalls at its barrier/lgkm wait the other blocks' waves keep issuing
// MFMA (m114 wave-level overlap); only 1/4 of the CU stalls per barrier.
// Per tile: 8 ds_read_b128/wave, lgkm0+barrier (buf dead), 4 gload_lds stage
// t+2, 16 MFMA, counted vmcnt(4) (t+1 certified, t+2 in flight), barrier.
// Granule swizzle slot=(g+(row>>1))&3, inverse-on-source / forward-on-read
// (0 conflicts, verified R2-R8; row stride 64 B unchanged).

#define BM 128
#define BN 128
#define BK 64
#define ATB 8192    // A tile bytes (128 x 64)
#define BTB 8192    // B tile bytes (128 x 64)

__global__ __launch_bounds__(256, 4) void lb_gemm_i8(
    const signed char* __restrict__ A,   // M x K i8 (quantized x)
    const signed char* __restrict__ B,   // N x K i8 {0,1} (binarized weight)
    const float* __restrict__ rscale,    // M row dequant scales
    const float* __restrict__ bias,
    float* __restrict__ C,
    int M, int N, int K)
{
    __shared__ signed char ldsA[2 * ATB];   // 16 KiB
    __shared__ signed char ldsB[2 * BTB];   // 16 KiB

    const int tid  = threadIdx.x;
    const int lane = tid & 63;
    const int wave = tid >> 6;       // 0..3
    const int wr   = wave >> 1;      // 0..1  -> 64 output rows each
    const int wc   = wave & 1;       // 0..1  -> 64 output cols each

    // XCD-aware bijective swizzle (grid % 8 == 0 guaranteed by launcher)
    int nwg = gridDim.x;
    int bid = blockIdx.x;
    bid = (bid & 7) * (nwg >> 3) + (bid >> 3);

    const int ntiles = N / BN;
    const int brow = (bid / ntiles) * BM;
    const int bcol = (bid % ntiles) * BN;

    const signed char* Abase = A + (size_t)brow * K;
    const signed char* Bbase = B + (size_t)bcol * K;

    // stage one 4 KiB chunk (64 rows x 64 B): linear LDS dest (tid*16),
    // inverse-swizzled global source. Each tile = 2 chunks per operand.
    const int srr = tid >> 2;        // 0..63 row within chunk
    const int sg  = tid & 3;         // stored slot
    auto stage = [&](const signed char* gbase, signed char* lbuf, int kt, int c) {
        int rr = c * 64 + srr;
        int gl = (sg - (rr >> 1)) & 3;
        const signed char* src = gbase + (size_t)rr * K + (size_t)kt * BK + gl * 16;
        signed char* dst = lbuf + c * 4096 + tid * 16;
        __builtin_amdgcn_global_load_lds(
            (const __attribute__((address_space(1))) void*)src,
            (__attribute__((address_space(3))) void*)dst, 16, 0, 0);
    };

    const int fr = lane & 15;
    const int fq = lane >> 4;                 // k-group
    const int sl = (fq + (fr >> 1)) & 3;      // stored slot for this lane

    int4v acc[4][4];
#pragma unroll
    for (int i = 0; i < 4; ++i)
#pragma unroll
        for (int j = 0; j < 4; ++j)
            acc[i][j] = (int4v){0, 0, 0, 0};

    const int nk = K / BK;   // >= 4 (launcher guard)

    // prologue: stage tiles 0 (buf0) and 1 (buf1); certify tile 0
#pragma unroll
    for (int t = 0; t < 2; ++t) {
        stage(Abase, &ldsA[t * ATB], t, 0);
        stage(Abase, &ldsA[t * ATB], t, 1);
        stage(Bbase, &ldsB[t * BTB], t, 0);
        stage(Bbase, &ldsB[t * BTB], t, 1);
    }
    asm volatile("s_waitcnt vmcnt(4)" ::: "memory");
    __builtin_amdgcn_s_barrier();

    int4v af[4], bf[4];

    for (int t = 0; t < nk; ++t) {
        const int p = t & 1;
        const signed char* ap = &ldsA[p * ATB + (wr * 64 + fr) * 64];
        const signed char* bp = &ldsB[p * BTB + (wc * 64 + fr) * 64];

        // read this tile's 8 fragments
#pragma unroll
        for (int m = 0; m < 4; ++m) af[m] = *(const int4v*)(ap + m * 1024 + sl * 16);
#pragma unroll
        for (int n = 0; n < 4; ++n) bf[n] = *(const int4v*)(bp + n * 1024 + sl * 16);
        asm volatile("s_waitcnt lgkmcnt(0)" ::: "memory");
        __builtin_amdgcn_sched_barrier(0);
        __builtin_amdgcn_s_barrier();          // all reads done -> buf p dead

        // stage tile t+2 into the just-freed buffer
        if (t + 2 < nk) {
            stage(Abase, &ldsA[p * ATB], t + 2, 0);
            stage(Abase, &ldsA[p * ATB], t + 2, 1);
            stage(Bbase, &ldsB[p * BTB], t + 2, 0);
            stage(Bbase, &ldsB[p * BTB], t + 2, 1);
        }

        __builtin_amdgcn_s_setprio(1);
#pragma unroll
        for (int m = 0; m < 4; ++m)
#pragma unroll
            for (int n = 0; n < 4; ++n)
                acc[m][n] = __builtin_amdgcn_mfma_i32_16x16x64_i8(
                    af[m], bf[n], acc[m][n], 0, 0, 0);
        __builtin_amdgcn_s_setprio(0);

        if (t < nk - 1) {
            // certify t+1's 4 loads; leave t+2's 4 in flight (counted)
            if (t + 2 < nk) asm volatile("s_waitcnt vmcnt(4)" ::: "memory");
            else            asm volatile("s_waitcnt vmcnt(0)" ::: "memory");
            __builtin_amdgcn_s_barrier();
        }
    }

    // epilogue: C/D layout col = lane&15, row = (lane>>4)*4 + reg
    float bn[4];
#pragma unroll
    for (int n = 0; n < 4; ++n)
        bn[n] = bias[bcol + wc * 64 + n * 16 + fr];

#pragma unroll
    for (int m = 0; m < 4; ++m) {
#pragma unroll
        for (int j = 0; j < 4; ++j) {
            int row = brow + wr * 64 + m * 16 + fq * 4 + j;
            float rs = rscale[row];
#pragma unroll
            for (int n = 0; n < 4; ++n) {
                int col = bcol + wc * 64 + n * 16 + fr;
                C[(size_t)row * N + col] = (float)acc[m][n][j] * rs + bn[n];
            }
        }
    }
}

// ---------- fallback: correct fp32 tiled GEMM ----------

__global__ __launch_bounds__(256) void lb_gemm_fb(
    const float* __restrict__ x, const float* __restrict__ w,
    const float* __restrict__ bias, float* __restrict__ C,
    int M, int N, int K)
{
    __shared__ float As[16][65];
    __shared__ float Bs[16][65];
    const int tid = threadIdx.x;
    const int tx = tid & 15, ty = tid >> 4;
    const int brow = blockIdx.y * 64, bcol = blockIdx.x * 64;

    float acc[4][4] = {};
    for (int kt = 0; kt < K; kt += 16) {
        for (int i = tid; i < 64 * 16; i += 256) {
            int r = i >> 4, k = i & 15;
            As[k][r] = x[(long)(brow + r) * K + kt + k];
        }
        for (int i = tid; i < 64 * 16; i += 256) {
            int n = i >> 4, k = i & 15;
            Bs[k][n] = (w[(long)(bcol + n) * K + kt + k] > 0.5f) ? 1.f : 0.f;
        }
        __syncthreads();
#pragma unroll
        for (int k = 0; k < 16; ++k) {
            float a[4], b[4];
#pragma unroll
            for (int i = 0; i < 4; ++i) a[i] = As[k][ty * 4 + i];
#pragma unroll
            for (int j = 0; j < 4; ++j) b[j] = Bs[k][tx * 4 + j];
#pragma unroll
            for (int i = 0; i < 4; ++i)
#pragma unroll
                for (int j = 0; j < 4; ++j)
                    acc[i][j] += a[i] * b[j];
        }
        __syncthreads();
    }
#pragma unroll
    for (int i = 0; i < 4; ++i)
#pragma unroll
        for (int j = 0; j < 4; ++j)
            C[(long)(brow + ty * 4 + i) * N + bcol + tx * 4 + j] = acc[i][j] + bias[bcol + tx * 4 + j];
}

// ---------- launcher ----------

extern "C" void kernel_launch(void* const* d_in, const int* in_sizes, int n_in,
                              void* d_out, int out_size, void* d_ws, size_t ws_size,
                              hipStream_t stream) {
    const float* x    = (const float*)d_in[0];
    const float* w    = (const float*)d_in[1];
    const float* bias = (const float*)d_in[2];
    float* out = (float*)d_out;

    const int N = in_sizes[2];                 // 4096
    const int K = in_sizes[1] / N;             // 4096
    const int M = in_sizes[0] / K;             // 8192

    const size_t need = (size_t)M * K + (size_t)N * K + (size_t)M * 4;
    const int ngrid = (M / BM) * (N / BN);     // 64*32 = 2048
    const bool ok = (ws_size >= need) && (M % BM == 0) && (N % BN == 0)
                    && (K % BK == 0) && (K / BK >= 4) && (ngrid % 8 == 0);

    if (ok) {
        signed char* xq = (signed char*)d_ws;
        signed char* wq = xq + (size_t)M * K;
        float* rscale   = (float*)(wq + (size_t)N * K);

        lb_quant_x<<<M, 256, 0, stream>>>(x, xq, rscale, K);
        long nw16 = (long)N * K / 16;
        lb_bin_w8<<<2048, 256, 0, stream>>>(w, (int4*)wq, nw16);

        lb_gemm_i8<<<dim3(ngrid), 256, 0, stream>>>(xq, wq, rscale, bias, out, M, N, K);
    } else {
        dim3 grid(N / 64, M / 64);
        lb_gemm_fb<<<grid, 256, 0, stream>>>(x, w, bias, out, M, N, K);
    }
}

// Round 10
// 189.750 us; speedup vs baseline: 1.1851x; 1.1851x over previous
//
#include <hip/hip_runtime.h>
#include <stdint.h>

typedef __attribute__((ext_vector_type(4))) int int4v;
typedef __attribute__((ext_vector_type(16))) int int16v;

// ---------- helpers ----------

__device__ __forceinline__ int pack4_rn(float4 v, float s) {
    int a = __float2int_rn(v.x * s) & 0xff;
    int b = __float2int_rn(v.y * s) & 0xff;
    int c = __float2int_rn(v.z * s) & 0xff;
    int d = __float2int_rn(v.w * s) & 0xff;
    return a | (b << 8) | (c << 16) | (d << 24);
}

__device__ __forceinline__ int bin4(float4 v) {
    int a = (v.x > 0.5f) ? 1 : 0;
    int b = (v.y > 0.5f) ? 1 : 0;
    int c = (v.z > 0.5f) ? 1 : 0;
    int d = (v.w > 0.5f) ? 1 : 0;
    return a | (b << 8) | (c << 16) | (d << 24);
}

// ---------- pre-pass: x (f32) -> per-row-quantized i8 + rscale ----------

__global__ __launch_bounds__(256) void lb_quant_x(const float* __restrict__ x,
        signed char* __restrict__ xq, float* __restrict__ rscale, int K)
{
    const int row = blockIdx.x;
    const int tid = threadIdx.x;
    const float* xr = x + (size_t)row * K;

    float mx = 0.f;
    for (int i = tid * 4; i < K; i += 256 * 4) {
        float4 v = *(const float4*)(xr + i);
        mx = fmaxf(mx, fmaxf(fmaxf(fabsf(v.x), fabsf(v.y)),
                             fmaxf(fabsf(v.z), fabsf(v.w))));
    }
#pragma unroll
    for (int s = 32; s; s >>= 1) mx = fmaxf(mx, __shfl_xor(mx, s));
    __shared__ float wmax[4];
    if ((tid & 63) == 0) wmax[tid >> 6] = mx;
    __syncthreads();
    mx = fmaxf(fmaxf(wmax[0], wmax[1]), fmaxf(wmax[2], wmax[3]));

    const float s = (mx > 0.f) ? 127.f / mx : 0.f;
    if (tid == 0) rscale[row] = (mx > 0.f) ? mx * (1.f / 127.f) : 0.f;

    for (int i = tid * 16; i < K; i += 256 * 16) {
        float4 a = *(const float4*)(xr + i);
        float4 b = *(const float4*)(xr + i + 4);
        float4 c = *(const float4*)(xr + i + 8);
        float4 d = *(const float4*)(xr + i + 12);
        int4 o;
        o.x = pack4_rn(a, s); o.y = pack4_rn(b, s);
        o.z = pack4_rn(c, s); o.w = pack4_rn(d, s);
        *(int4*)(xq + (size_t)row * K + i) = o;
    }
}

// ---------- pre-pass: w (f32) -> binarized i8 {0,1} ----------

__global__ void lb_bin_w8(const float* __restrict__ w, int4* __restrict__ wq, long n16) {
    long i = (long)blockIdx.x * blockDim.x + threadIdx.x;
    long stride = (long)gridDim.x * blockDim.x;
    for (; i < n16; i += stride) {
        const float4* p = (const float4*)w + i * 4;
        float4 v0 = p[0], v1 = p[1], v2 = p[2], v3 = p[3];
        int4 o;
        o.x = bin4(v0); o.y = bin4(v1); o.z = bin4(v2); o.w = bin4(v3);
        wq[i] = o;
    }
}

// ---------- main GEMM (i8, 32x32x32): 256x256, BK=64, quad-buffered ----------
// R6 skeleton verbatim (quad-buffer, distance-3 prefetch, 2 phases/tile,
// counted vmcnt(8), granule swizzle inverse-on-source / forward-on-read).
// ONLY change: mfma_i32_32x32x32_i8 (4404 TOPS ubench vs 3944 for 16x16x64;
// 16 long MFMA/tile/wave instead of 32 short -> half the issue slots).
// Wave tile 128x64 = 4x2 frags of 32x32. Per tile: 12 ds_read_b128 (8 A+4 B).
// A frag: row=lane&31, k-bytes (lane>>5)*16 (K-chunk rule, verified analog);
// C/D: col=lane&31, row=(reg&3)+8*(reg>>2)+4*(lane>>5) [m74/m101].

#define BM 256
#define BN 256
#define BK 64
#define TBYTES 16384   // bytes per LDS buffer (256 rows x 64 B)

#define PHASE_SYNC do { \
    __builtin_amdgcn_s_barrier(); \
    asm volatile("s_waitcnt lgkmcnt(0)" ::: "memory"); \
    __builtin_amdgcn_sched_barrier(0); \
} while (0)

// 8 MFMA for row-half MH (mi = MH*2, MH*2+1), both ni, both kg
#define MFMA8H(MH) do { \
    __builtin_amdgcn_s_setprio(1); \
    _Pragma("unroll") \
    for (int mi_ = (MH)*2; mi_ < (MH)*2 + 2; ++mi_) { \
      _Pragma("unroll") \
      for (int ni_ = 0; ni_ < 2; ++ni_) { \
        _Pragma("unroll") \
        for (int kg_ = 0; kg_ < 2; ++kg_) { \
          acc[mi_][ni_] = __builtin_amdgcn_mfma_i32_32x32x32_i8( \
              af[mi_][kg_], bf[ni_][kg_], acc[mi_][ni_], 0, 0, 0); \
        } \
      } \
    } \
    __builtin_amdgcn_s_setprio(0); \
} while (0)

__global__ __launch_bounds__(512, 2) void lb_gemm256_i8(
    const signed char* __restrict__ A,   // M x K i8 (quantized x)
    const signed char* __restrict__ B,   // N x K i8 {0,1} (binarized weight)
    const float* __restrict__ rscale,    // M row dequant scales
    const float* __restrict__ bias,
    float* __restrict__ C,
    int M, int N, int K)
{
    __shared__ signed char ldsA[4 * TBYTES];   // 64 KiB
    __shared__ signed char ldsB[4 * TBYTES];   // 64 KiB

    const int tid  = threadIdx.x;
    const int lane = tid & 63;
    const int wave = tid >> 6;       // 0..7
    const int wr   = wave >> 2;      // 0..1  -> 128 output rows
    const int wc   = wave & 3;       // 0..3  -> 64 output cols

    // XCD-aware bijective swizzle (grid % 8 == 0 guaranteed by launcher)
    int nwg = gridDim.x;
    int bid = blockIdx.x;
    bid = (bid & 7) * (nwg >> 3) + (bid >> 3);

    const int ntiles = N / BN;
    const int brow = (bid / ntiles) * BM;
    const int bcol = (bid % ntiles) * BN;

    const signed char* Abase = A + (size_t)brow * K;
    const signed char* Bbase = B + (size_t)bcol * K;

    // stage one 8 KiB chunk (128 rows x 64 B): linear LDS dest (tid*16),
    // inverse-swizzled global source (slot=(g+(row>>1))&3)
    const int srr = tid >> 2;
    const int sg  = tid & 3;
    auto stage = [&](const signed char* gbase, signed char* lbuf, int kt, int c) {
        int rr = c * 128 + srr;
        int gl = (sg - (rr >> 1)) & 3;
        const signed char* src = gbase + (size_t)rr * K + (size_t)kt * BK + gl * 16;
        signed char* dst = lbuf + c * 8192 + tid * 16;
        __builtin_amdgcn_global_load_lds(
            (const __attribute__((address_space(1))) void*)src,
            (__attribute__((address_space(3))) void*)dst, 16, 0, 0);
    };

    // 32x32 fragment addressing
    const int r32 = lane & 31;                // A-row / B-col within 32-block
    const int kh  = lane >> 5;                // k-half within 32-K (16 B each)

    int16v acc[4][2];
#pragma unroll
    for (int i = 0; i < 4; ++i)
#pragma unroll
        for (int j = 0; j < 2; ++j)
#pragma unroll
            for (int r = 0; r < 16; ++r)
                acc[i][j][r] = 0;

    const int nk = K / BK;   // >= 4 (launcher guard)

    // prologue: stage tiles 0,1,2; certify tile 0
#pragma unroll
    for (int t = 0; t < 3; ++t) {
        stage(Bbase, &ldsB[t * TBYTES], t, 0); stage(Bbase, &ldsB[t * TBYTES], t, 1);
        stage(Abase, &ldsA[t * TBYTES], t, 0); stage(Abase, &ldsA[t * TBYTES], t, 1);
    }
    asm volatile("s_waitcnt vmcnt(8)" ::: "memory");
    __builtin_amdgcn_s_barrier();

    int4v af[4][2], bf[2][2];

    for (int t = 0; t < nk; ++t) {
        const int buf = t & 3;
        const signed char* ab = &ldsA[buf * TBYTES];
        const signed char* bb = &ldsB[buf * TBYTES];
        const bool pf = (t + 3 < nk);
        const int sb = (t + 3) & 3;

        // ---- phase A: af[0..1][*] + bf[0..1][*] (8 reads); stage B of t+3 ----
#pragma unroll
        for (int mi = 0; mi < 2; ++mi) {
#pragma unroll
            for (int kg = 0; kg < 2; ++kg) {
                int row = wr * 128 + mi * 32 + r32;
                int slot = ((kg * 2 + kh) + (row >> 1)) & 3;
                af[mi][kg] = *(const int4v*)(ab + row * 64 + slot * 16);
            }
        }
#pragma unroll
        for (int ni = 0; ni < 2; ++ni) {
#pragma unroll
            for (int kg = 0; kg < 2; ++kg) {
                int col = wc * 64 + ni * 32 + r32;
                int slot = ((kg * 2 + kh) + (col >> 1)) & 3;
                bf[ni][kg] = *(const int4v*)(bb + col * 64 + slot * 16);
            }
        }
        if (pf) { stage(Bbase, &ldsB[sb * TBYTES], t + 3, 0);
                  stage(Bbase, &ldsB[sb * TBYTES], t + 3, 1); }
        PHASE_SYNC;
        MFMA8H(0);

        // ---- phase B: af[2..3][*] (4 reads); stage A of t+3; counted vmcnt ----
#pragma unroll
        for (int mi = 2; mi < 4; ++mi) {
#pragma unroll
            for (int kg = 0; kg < 2; ++kg) {
                int row = wr * 128 + mi * 32 + r32;
                int slot = ((kg * 2 + kh) + (row >> 1)) & 3;
                af[mi][kg] = *(const int4v*)(ab + row * 64 + slot * 16);
            }
        }
        if (pf) { stage(Abase, &ldsA[sb * TBYTES], t + 3, 0);
                  stage(Abase, &ldsA[sb * TBYTES], t + 3, 1); }
        if (pf)               asm volatile("s_waitcnt vmcnt(8)" ::: "memory");
        else if (t == nk - 3) asm volatile("s_waitcnt vmcnt(4)" ::: "memory");
        else if (t == nk - 2) asm volatile("s_waitcnt vmcnt(0)" ::: "memory");
        PHASE_SYNC;
        MFMA8H(1);
    }

    // epilogue: 32x32 C/D layout col=lane&31, row=(reg&3)+8*(reg>>2)+4*(lane>>5)
    float bn[2];
#pragma unroll
    for (int ni = 0; ni < 2; ++ni)
        bn[ni] = bias[bcol + wc * 64 + ni * 32 + r32];

#pragma unroll
    for (int mi = 0; mi < 4; ++mi) {
#pragma unroll
        for (int reg = 0; reg < 16; ++reg) {
            int row = brow + wr * 128 + mi * 32 + (reg & 3) + 8 * (reg >> 2) + 4 * kh;
            float rs = rscale[row];
#pragma unroll
            for (int ni = 0; ni < 2; ++ni) {
                int col = bcol + wc * 64 + ni * 32 + r32;
                C[(size_t)row * N + col] = (float)acc[mi][ni][reg] * rs + bn[ni];
            }
        }
    }
}

// ---------- fallback: correct fp32 tiled GEMM ----------

__global__ __launch_bounds__(256) void lb_gemm_fb(
    const float* __restrict__ x, const float* __restrict__ w,
    const float* __restrict__ bias, float* __restrict__ C,
    int M, int N, int K)
{
    __shared__ float As[16][65];
    __shared__ float Bs[16][65];
    const int tid = threadIdx.x;
    const int tx = tid & 15, ty = tid >> 4;
    const int brow = blockIdx.y * 64, bcol = blockIdx.x * 64;

    float acc[4][4] = {};
    for (int kt = 0; kt < K; kt += 16) {
        for (int i = tid; i < 64 * 16; i += 256) {
            int r = i >> 4, k = i & 15;
            As[k][r] = x[(long)(brow + r) * K + kt + k];
        }
        for (int i = tid; i < 64 * 16; i += 256) {
            int n = i >> 4, k = i & 15;
            Bs[k][n] = (w[(long)(bcol + n) * K + kt + k] > 0.5f) ? 1.f : 0.f;
        }
        __syncthreads();
#pragma unroll
        for (int k = 0; k < 16; ++k) {
            float a[4], b[4];
#pragma unroll
            for (int i = 0; i < 4; ++i) a[i] = As[k][ty * 4 + i];
#pragma unroll
            for (int j = 0; j < 4; ++j) b[j] = Bs[k][tx * 4 + j];
#pragma unroll
            for (int i = 0; i < 4; ++i)
#pragma unroll
                for (int j = 0; j < 4; ++j)
                    acc[i][j] += a[i] * b[j];
        }
        __syncthreads();
    }
#pragma unroll
    for (int i = 0; i < 4; ++i)
#pragma unroll
        for (int j = 0; j < 4; ++j)
            C[(long)(brow + ty * 4 + i) * N + bcol + tx * 4 + j] = acc[i][j] + bias[bcol + tx * 4 + j];
}

// ---------- launcher ----------

extern "C" void kernel_launch(void* const* d_in, const int* in_sizes, int n_in,
                              void* d_out, int out_size, void* d_ws, size_t ws_size,
                              hipStream_t stream) {
    const float* x    = (const float*)d_in[0];
    const float* w    = (const float*)d_in[1];
    const float* bias = (const float*)d_in[2];
    float* out = (float*)d_out;

    const int N = in_sizes[2];                 // 4096
    const int K = in_sizes[1] / N;             // 4096
    const int M = in_sizes[0] / K;             // 8192

    const size_t need = (size_t)M * K + (size_t)N * K + (size_t)M * 4;
    const int ngrid = (M / BM) * (N / BN);     // 32*16 = 512
    const bool ok = (ws_size >= need) && (M % BM == 0) && (N % BN == 0)
                    && (K % BK == 0) && (K / BK >= 4) && (ngrid % 8 == 0);

    if (ok) {
        signed char* xq = (signed char*)d_ws;
        signed char* wq = xq + (size_t)M * K;
        float* rscale   = (float*)(wq + (size_t)N * K);

        lb_quant_x<<<M, 256, 0, stream>>>(x, xq, rscale, K);
        long nw16 = (long)N * K / 16;
        lb_bin_w8<<<2048, 256, 0, stream>>>(w, (int4*)wq, nw16);

        lb_gemm256_i8<<<dim3(ngrid), 512, 0, stream>>>(xq, wq, rscale, bias, out, M, N, K);
    } else {
        dim3 grid(N / 64, M / 64);
        lb_gemm_fb<<<grid, 256, 0, stream>>>(x, w, bias, out, M, N, K);
    }
}